// Round 1
// baseline (356.520 us; speedup 1.0000x reference)
//
#include <hip/hip_runtime.h>
#include <hip/hip_bf16.h>

// Problem: C[m][o] = sum_i x[m][i] * ternary[o][i] * scales[o*32 + i/128]
//   M = 4*2048 = 8192, N = 4096 (out features), K = 4096 (in features)
// Plan: prepass x(fp32)->bf16 and W dequant(int32,scale)->bf16 into d_ws,
//       then m97-style 128x128 bf16 NT-GEMM (global_load_lds, 16x16x32 MFMA).

#define Msz 8192
#define Nsz 4096
#define Ksz 4096

typedef __attribute__((ext_vector_type(8))) short short8;
typedef __attribute__((ext_vector_type(4))) float f32x4;
typedef __attribute__((ext_vector_type(4))) int int4v;
typedef __attribute__((ext_vector_type(4))) float float4v;
typedef __attribute__((ext_vector_type(8))) unsigned short ushort8;

// round-to-nearest-even fp32 -> bf16 (inputs are finite normals)
static __device__ __forceinline__ unsigned short f2bf(float f) {
    unsigned u = __builtin_bit_cast(unsigned, f);
    u += 0x7fffu + ((u >> 16) & 1u);
    return (unsigned short)(u >> 16);
}

// ---------------- prepass 1: x fp32 -> bf16 ----------------
__global__ void cvt_x(const float* __restrict__ x, unsigned short* __restrict__ o, int n8) {
    int i = blockIdx.x * blockDim.x + threadIdx.x;
    int stride = gridDim.x * blockDim.x;
    for (; i < n8; i += stride) {
        const float4v* p = (const float4v*)x + (size_t)i * 2;
        float4v a = p[0], b = p[1];
        ushort8 r;
        r[0] = f2bf(a[0]); r[1] = f2bf(a[1]); r[2] = f2bf(a[2]); r[3] = f2bf(a[3]);
        r[4] = f2bf(b[0]); r[5] = f2bf(b[1]); r[6] = f2bf(b[2]); r[7] = f2bf(b[3]);
        *((ushort8*)o + i) = r;
    }
}

// ---------------- prepass 2: W = ternary * group_scale -> bf16 ----------------
// flat element e = i*8 ; group = e/128 = i/16 (8-aligned chunk stays in one group)
__global__ void dequant_w(const int* __restrict__ t, const float* __restrict__ s,
                          unsigned short* __restrict__ o, int n8) {
    int i = blockIdx.x * blockDim.x + threadIdx.x;
    int stride = gridDim.x * blockDim.x;
    for (; i < n8; i += stride) {
        float sc = s[i >> 4];
        const int4v* p = (const int4v*)t + (size_t)i * 2;
        int4v a = p[0], b = p[1];
        ushort8 r;
        r[0] = f2bf((float)a[0] * sc); r[1] = f2bf((float)a[1] * sc);
        r[2] = f2bf((float)a[2] * sc); r[3] = f2bf((float)a[3] * sc);
        r[4] = f2bf((float)b[0] * sc); r[5] = f2bf((float)b[1] * sc);
        r[6] = f2bf((float)b[2] * sc); r[7] = f2bf((float)b[3] * sc);
        *((ushort8*)o + i) = r;
    }
}

// ---------------- main GEMM: m97 structure ----------------
// 128x128 tile, BK=32, 4 waves (2x2), each wave 64x64 out = 4x4 frags of 16x16,
// v_mfma_f32_16x16x32_bf16, global_load_lds width 16 staging, single LDS buffer.
#define BM 128
#define BN 128
#define BKT 32

__global__ void gemm_bt(const unsigned short* __restrict__ A,
                        const unsigned short* __restrict__ B,
                        float* __restrict__ C) {
    __shared__ unsigned short sA[BM * BKT]; // [128][32] row-major, 8 KB
    __shared__ unsigned short sB[BN * BKT];

    const int tid  = threadIdx.x;
    const int lane = tid & 63;
    const int wid  = tid >> 6;
    const int wr   = wid >> 1;  // wave row (0..1)
    const int wc   = wid & 1;   // wave col (0..1)
    const int rowBase = blockIdx.y * BM;
    const int colBase = blockIdx.x * BN;

    f32x4 acc[4][4] = {};

    // staging lane geometry: 1 KB chunk = 16 rows x 64 B; lane l -> row l/4, col-elems (l&3)*8
    const int srow = lane >> 2;        // 0..15
    const int scol = (lane & 3) * 8;   // element col within BK tile

    const unsigned short* gA = A + (size_t)(rowBase + wid * 32 + srow) * Ksz + scol;
    const unsigned short* gB = B + (size_t)(colBase + wid * 32 + srow) * Ksz + scol;

    const int frow = lane & 15;          // fragment row within 16
    const int fcol = (lane >> 4) * 8;    // k-offset within 32

    for (int kt = 0; kt < Ksz / BKT; ++kt) {
        const unsigned short* ga = gA + kt * BKT;
        const unsigned short* gb = gB + kt * BKT;
#pragma unroll
        for (int c = 0; c < 2; ++c) {
            __builtin_amdgcn_global_load_lds(
                (const __attribute__((address_space(1))) void*)(ga + (size_t)c * 16 * Ksz),
                (__attribute__((address_space(3))) void*)(&sA[(wid * 32 + c * 16) * BKT]),
                16, 0, 0);
            __builtin_amdgcn_global_load_lds(
                (const __attribute__((address_space(1))) void*)(gb + (size_t)c * 16 * Ksz),
                (__attribute__((address_space(3))) void*)(&sB[(wid * 32 + c * 16) * BKT]),
                16, 0, 0);
        }
        __syncthreads();

        short8 af[4], bfr[4];
#pragma unroll
        for (int m = 0; m < 4; ++m)
            af[m] = *(const short8*)&sA[(wr * 64 + m * 16 + frow) * BKT + fcol];
#pragma unroll
        for (int n = 0; n < 4; ++n)
            bfr[n] = *(const short8*)&sB[(wc * 64 + n * 16 + frow) * BKT + fcol];
#pragma unroll
        for (int m = 0; m < 4; ++m)
#pragma unroll
            for (int n = 0; n < 4; ++n)
                acc[m][n] = __builtin_amdgcn_mfma_f32_16x16x32_bf16(af[m], bfr[n], acc[m][n], 0, 0, 0);
        __syncthreads();
    }

    // epilogue: C/D layout (16x16x32): col = lane&15, row = (lane>>4)*4 + j
    const int crow0 = rowBase + wr * 64 + (lane >> 4) * 4;
    const int ccol0 = colBase + wc * 64 + (lane & 15);
#pragma unroll
    for (int m = 0; m < 4; ++m)
#pragma unroll
        for (int n = 0; n < 4; ++n) {
            float* cp = C + (size_t)(crow0 + m * 16) * Nsz + ccol0 + n * 16;
#pragma unroll
            for (int j = 0; j < 4; ++j)
                cp[(size_t)j * Nsz] = acc[m][n][j];
        }
}

// ---------------- fallback (ws too small): exact fp32, slow but correct ----------------
__global__ void gemm_naive(const float* __restrict__ x, const int* __restrict__ t,
                           const float* __restrict__ s, float* __restrict__ C) {
    size_t o = (size_t)blockIdx.x * blockDim.x + threadIdx.x;
    if (o >= (size_t)Msz * Nsz) return;
    int m = (int)(o / Nsz), n = (int)(o % Nsz);
    float acc = 0.f;
    for (int g = 0; g < Ksz / 128; ++g) {
        float sc = s[n * (Ksz / 128) + g];
        float p = 0.f;
        const float* xp = x + (size_t)m * Ksz + g * 128;
        const int* tp = t + (size_t)n * Ksz + g * 128;
        for (int k = 0; k < 128; ++k) p += xp[k] * (float)tp[k];
        acc += sc * p;
    }
    C[o] = acc;
}

extern "C" void kernel_launch(void* const* d_in, const int* in_sizes, int n_in,
                              void* d_out, int out_size, void* d_ws, size_t ws_size,
                              hipStream_t stream) {
    const float* x      = (const float*)d_in[0];
    const int*   tern   = (const int*)d_in[1];
    const float* scales = (const float*)d_in[2];
    float* out = (float*)d_out;

    const size_t aBytes = (size_t)Msz * Ksz * 2; // 64 MiB
    const size_t bBytes = (size_t)Nsz * Ksz * 2; // 32 MiB

    if (ws_size >= aBytes + bBytes) {
        unsigned short* Abf = (unsigned short*)d_ws;
        unsigned short* Bbf = (unsigned short*)((char*)d_ws + aBytes);
        cvt_x<<<2048, 256, 0, stream>>>(x, Abf, (int)((size_t)Msz * Ksz / 8));
        dequant_w<<<2048, 256, 0, stream>>>(tern, scales, Bbf, (int)((size_t)Nsz * Ksz / 8));
        dim3 grid(Nsz / BN, Msz / BM);
        gemm_bt<<<grid, 256, 0, stream>>>(Abf, Bbf, out);
    } else {
        gemm_naive<<<(int)(((size_t)Msz * Nsz + 255) / 256), 256, 0, stream>>>(x, tern, scales, out);
    }
}

// Round 2
// 278.994 us; speedup vs baseline: 1.2779x; 1.2779x over previous
//
#include <hip/hip_runtime.h>
#include <hip/hip_bf16.h>

// C[m][o] = sum_i x[m][i] * ternary[o][i] * scales[o*32 + i/128]
// M=8192, N=4096, K=4096. Prepass to bf16 (x cvt, W dequant) in d_ws,
// then 256x256 8-phase bf16 NT-GEMM (T2 swizzle + T3/T4 counted vmcnt + T5 setprio).

#define Msz 8192
#define Nsz 4096
#define Ksz 4096

typedef __attribute__((ext_vector_type(8))) short short8;
typedef __attribute__((ext_vector_type(4))) float f32x4;
typedef __attribute__((ext_vector_type(4))) int int4v;
typedef __attribute__((ext_vector_type(4))) float float4v;
typedef __attribute__((ext_vector_type(8))) unsigned short ushort8;

static __device__ __forceinline__ unsigned short f2bf(float f) {
    unsigned u = __builtin_bit_cast(unsigned, f);
    u += 0x7fffu + ((u >> 16) & 1u);
    return (unsigned short)(u >> 16);
}

// ---------------- prepass 1: x fp32 -> bf16 ----------------
__global__ void cvt_x(const float* __restrict__ x, unsigned short* __restrict__ o, int n8) {
    int i = blockIdx.x * blockDim.x + threadIdx.x;
    int stride = gridDim.x * blockDim.x;
    for (; i < n8; i += stride) {
        const float4v* p = (const float4v*)x + (size_t)i * 2;
        float4v a = p[0], b = p[1];
        ushort8 r;
        r[0] = f2bf(a[0]); r[1] = f2bf(a[1]); r[2] = f2bf(a[2]); r[3] = f2bf(a[3]);
        r[4] = f2bf(b[0]); r[5] = f2bf(b[1]); r[6] = f2bf(b[2]); r[7] = f2bf(b[3]);
        *((ushort8*)o + i) = r;
    }
}

// ---------------- prepass 2: W = ternary * group_scale -> bf16 ----------------
__global__ void dequant_w(const int* __restrict__ t, const float* __restrict__ s,
                          unsigned short* __restrict__ o, int n8) {
    int i = blockIdx.x * blockDim.x + threadIdx.x;
    int stride = gridDim.x * blockDim.x;
    for (; i < n8; i += stride) {
        float sc = s[i >> 4];
        const int4v* p = (const int4v*)t + (size_t)i * 2;
        int4v a = p[0], b = p[1];
        ushort8 r;
        r[0] = f2bf((float)a[0] * sc); r[1] = f2bf((float)a[1] * sc);
        r[2] = f2bf((float)a[2] * sc); r[3] = f2bf((float)a[3] * sc);
        r[4] = f2bf((float)b[0] * sc); r[5] = f2bf((float)b[1] * sc);
        r[6] = f2bf((float)b[2] * sc); r[7] = f2bf((float)b[3] * sc);
        *((ushort8*)o + i) = r;
    }
}

// ---------------- main GEMM: 256x256 8-phase template ----------------
// 8 waves (2M x 4N), per-wave 128x64 out = 8x4 frags; BK=64 (2 k-steps of 32).
// LDS: 2 buf x {A,B} x 32KB, subtile-blocked [R/16][K/32][16][32] bf16,
// XOR-swizzle: byte ^= ((byte>>9)&1)<<5 within each 1024B subtile.
// Staging: K-half granularity (16KB = 2 x global_load_lds x16B per thread),
// one half-stage per phase; waits: vmcnt(4) at phases 4 and 8 only.

#define DSREADS_AB(b, qm, ks) {                                                  \
    _Pragma("unroll") for (int n = 0; n < 4; ++n)                                \
      bfr[n] = *(const short8*)(L + (b)*65536 + 32768 + ((((wc)*4+n)*2+(ks))<<10) + laneA); \
    _Pragma("unroll") for (int m = 0; m < 4; ++m)                                \
      af[m] = *(const short8*)(L + (b)*65536 + ((((wr)*8+(qm)*4+m)*2+(ks))<<10) + laneA); }

#define DSREADS_A(b, qm, ks) {                                                   \
    _Pragma("unroll") for (int m = 0; m < 4; ++m)                                \
      af[m] = *(const short8*)(L + (b)*65536 + ((((wr)*8+(qm)*4+m)*2+(ks))<<10) + laneA); }

#define MFMAS(qm) {                                                              \
    _Pragma("unroll") for (int m = 0; m < 4; ++m)                                \
    _Pragma("unroll") for (int n = 0; n < 4; ++n)                                \
      acc[(qm)*4+m][n] = __builtin_amdgcn_mfma_f32_16x16x32_bf16(af[m], bfr[n], acc[(qm)*4+m][n], 0, 0, 0); }

// MOFF: A=0, B=32768. BOFF: buf0=0, buf1=65536. T: K-tile idx, KH: k-half 0/1.
#define STAGE(PMAT, MOFF, BOFF, T, KH) {                                         \
    _Pragma("unroll") for (int j = 0; j < 2; ++j)                                \
      __builtin_amdgcn_global_load_lds(                                          \
        (const __attribute__((address_space(1))) void*)(PMAT[j] + (T)*64 + (KH)*32), \
        (__attribute__((address_space(3))) void*)(L + (BOFF) + (MOFF) + dOff[j] + (KH)*1024), \
        16, 0, 0); }

#define WAITV4 asm volatile("s_waitcnt vmcnt(4)" ::: "memory");

#define PHASE(READS, QM, STG, WV)                                                \
    READS;                                                                       \
    STG;                                                                         \
    __builtin_amdgcn_sched_barrier(0);                                           \
    __builtin_amdgcn_s_barrier();                                                \
    asm volatile("s_waitcnt lgkmcnt(0)" ::: "memory");                           \
    __builtin_amdgcn_sched_barrier(0);                                           \
    __builtin_amdgcn_s_setprio(1);                                               \
    MFMAS(QM);                                                                   \
    __builtin_amdgcn_s_setprio(0);                                               \
    WV;                                                                          \
    __builtin_amdgcn_sched_barrier(0);                                           \
    __builtin_amdgcn_s_barrier();                                                \
    __builtin_amdgcn_sched_barrier(0);

__global__ __launch_bounds__(512, 2) void gemm_8p(const unsigned short* __restrict__ A,
                                                  const unsigned short* __restrict__ B,
                                                  float* __restrict__ C) {
    __shared__ __align__(16) unsigned char L[131072]; // 128 KiB

    const int tid  = threadIdx.x;
    const int lane = tid & 63;
    const int wid  = tid >> 6;
    const int wr   = wid >> 2;   // 0..1
    const int wc   = wid & 3;    // 0..3
    const int rowBase = blockIdx.y * 256;
    const int colBase = blockIdx.x * 256;

    // reader per-lane byte offset within a subtile (+swizzle):
    //   r=lane&15, c=lane>>4 : (r*64 + c*16) ^ ((r&8)<<2)
    const int laneA = (((lane & 15) * 64) + ((lane >> 4) * 16)) ^ (((lane >> 3) & 1) << 5);

    // stager: chunk w=lane -> logical (r,kloc) such that linear dest + swizzled
    // read form the same involution (rule 21):
    //   r = w>>2 ; kloc = (w&1)*8 + (((w>>1)^(w>>5))&1)*16
    const int kloc = (lane & 1) * 8 + (((lane >> 1) ^ (lane >> 5)) & 1) * 16;
    const int r_st = lane >> 2;
    const unsigned short* pA[2];
    const unsigned short* pB[2];
    int dOff[2];
#pragma unroll
    for (int j = 0; j < 2; ++j) {
        int R = (j * 8 + wid) * 16 + r_st;
        pA[j] = A + (size_t)(rowBase + R) * Ksz + kloc;
        pB[j] = B + (size_t)(colBase + R) * Ksz + kloc;
        dOff[j] = (j * 8 + wid) * 2048;
    }

    f32x4 acc[8][4] = {};
    short8 af[4], bfr[4];

    // ---- prologue: T0 (all 4 half-stages) -> buf0, T1 kh0 -> buf1 ----
    STAGE(pA, 0,     0,     0, 0);
    STAGE(pB, 32768, 0,     0, 0);
    STAGE(pA, 0,     0,     0, 1);
    STAGE(pB, 32768, 0,     0, 1);
    STAGE(pA, 0,     65536, 1, 0);
    STAGE(pB, 32768, 65536, 1, 0);
    WAITV4                          // T0's 8 loads retired; T1-kh0 may fly
    __builtin_amdgcn_sched_barrier(0);
    __builtin_amdgcn_s_barrier();
    __builtin_amdgcn_sched_barrier(0);

    for (int i = 0; i < 32; ++i) {
        const int t1 = 2 * i + 1;
        const int t2 = (i < 31) ? 2 * i + 2 : 62;  // clamp: last-iter stages are dead writes
        const int t3 = (i < 31) ? 2 * i + 3 : 62;  // into freed regions (addresses valid)

        // tile T0=2i in buf0 (phases 1-4), T1=2i+1 in buf1 (phases 5-8)
        PHASE(DSREADS_AB(0, 0, 0), 0, STAGE(pA, 0,     65536, t1, 1), )
        PHASE(DSREADS_A (0, 1, 0), 1, STAGE(pB, 32768, 65536, t1, 1), )
        PHASE(DSREADS_AB(0, 1, 1), 1, STAGE(pA, 0,     0,     t2, 0), )
        PHASE(DSREADS_A (0, 0, 1), 0, STAGE(pB, 32768, 0,     t2, 0), WAITV4)
        PHASE(DSREADS_AB(1, 0, 0), 0, STAGE(pA, 0,     0,     t2, 1), )
        PHASE(DSREADS_A (1, 1, 0), 1, STAGE(pB, 32768, 0,     t2, 1), )
        PHASE(DSREADS_AB(1, 1, 1), 1, STAGE(pA, 0,     65536, t3, 0), )
        PHASE(DSREADS_A (1, 0, 1), 0, STAGE(pB, 32768, 65536, t3, 0), WAITV4)
    }

    // drain outstanding gload_lds before LDS teardown / endpgm
    asm volatile("s_waitcnt vmcnt(0)" ::: "memory");

    // epilogue: C/D layout (16x16x32): col = lane&15, row = (lane>>4)*4 + j
    const int crow0 = rowBase + wr * 128 + (lane >> 4) * 4;
    const int ccol0 = colBase + wc * 64 + (lane & 15);
#pragma unroll
    for (int fm = 0; fm < 8; ++fm)
#pragma unroll
        for (int fn = 0; fn < 4; ++fn) {
            float* cp = C + (size_t)(crow0 + fm * 16) * Nsz + ccol0 + fn * 16;
#pragma unroll
            for (int j = 0; j < 4; ++j)
                cp[(size_t)j * Nsz] = acc[fm][fn][j];
        }
}

// ---------------- fallback (ws too small): exact fp32, slow but correct ----------------
__global__ void gemm_naive(const float* __restrict__ x, const int* __restrict__ t,
                           const float* __restrict__ s, float* __restrict__ C) {
    size_t o = (size_t)blockIdx.x * blockDim.x + threadIdx.x;
    if (o >= (size_t)Msz * Nsz) return;
    int m = (int)(o / Nsz), n = (int)(o % Nsz);
    float acc = 0.f;
    for (int g = 0; g < Ksz / 128; ++g) {
        float sc = s[n * (Ksz / 128) + g];
        float p = 0.f;
        const float* xp = x + (size_t)m * Ksz + g * 128;
        const int* tp = t + (size_t)n * Ksz + g * 128;
        for (int k = 0; k < 128; ++k) p += xp[k] * (float)tp[k];
        acc += sc * p;
    }
    C[o] = acc;
}

extern "C" void kernel_launch(void* const* d_in, const int* in_sizes, int n_in,
                              void* d_out, int out_size, void* d_ws, size_t ws_size,
                              hipStream_t stream) {
    const float* x      = (const float*)d_in[0];
    const int*   tern   = (const int*)d_in[1];
    const float* scales = (const float*)d_in[2];
    float* out = (float*)d_out;

    const size_t aBytes = (size_t)Msz * Ksz * 2; // 64 MiB
    const size_t bBytes = (size_t)Nsz * Ksz * 2; // 32 MiB

    if (ws_size >= aBytes + bBytes) {
        unsigned short* Abf = (unsigned short*)d_ws;
        unsigned short* Bbf = (unsigned short*)((char*)d_ws + aBytes);
        cvt_x<<<2048, 256, 0, stream>>>(x, Abf, (int)((size_t)Msz * Ksz / 8));
        dequant_w<<<2048, 256, 0, stream>>>(tern, scales, Bbf, (int)((size_t)Nsz * Ksz / 8));
        dim3 grid(Nsz / 256, Msz / 256);
        gemm_8p<<<grid, 512, 0, stream>>>(Abf, Bbf, out);
    } else {
        gemm_naive<<<(int)(((size_t)Msz * Nsz + 255) / 256), 256, 0, stream>>>(x, tern, scales, out);
    }
}